// Round 5
// baseline (20875.250 us; speedup 1.0000x reference)
//
#include <hip/hip_runtime.h>

#define RK 32          // workgroups per LSTM direction
#define RTH 1024       // threads per recurrence WG
#define UPS 16         // hidden units per slot (512/RK)
#define SEQ 4096
#define HID 512
#define NT 24

__device__ __forceinline__ float sigf(float x) { return 1.f / (1.f + __expf(-x)); }
__device__ __forceinline__ float tanhfast(float x) {
    const float e = __expf(2.f * x);
    return 1.f - 2.f / (e + 1.f);
}

__device__ __forceinline__ bool ok4(const float4& v, float lo, float hi) {
    return v.x >= lo && v.x <= hi && v.y >= lo && v.y <= hi &&
           v.z >= lo && v.z <= hi && v.w >= lo && v.w <= hi;
}

// 64B line load (4x16B), L1+L2 bypass -> coherent mall snapshot, one
// round trip for all four (single vmcnt(0)).
// gfx950 VMEM syntax: offset: immediate must PRECEDE cache flags (r4 fix).
__device__ __forceinline__ void load_line_cc(const float* p, float4& a, float4& b,
                                             float4& c, float4& d) {
    asm volatile(
        "global_load_dwordx4 %0, %4, off sc0 sc1\n\t"
        "global_load_dwordx4 %1, %4, off offset:16 sc0 sc1\n\t"
        "global_load_dwordx4 %2, %4, off offset:32 sc0 sc1\n\t"
        "global_load_dwordx4 %3, %4, off offset:48 sc0 sc1\n\t"
        "s_waitcnt vmcnt(0)"
        : "=v"(a), "=v"(b), "=v"(c), "=v"(d)
        : "v"(p) : "memory");
}

// ---------------- init: embedding gather ----------------
__global__ __launch_bounds__(64)
void init_gather(const float* __restrict__ emb, const int* __restrict__ sent,
                 float* __restrict__ X0)
{
    const int b = blockIdx.x, tid = threadIdx.x;
    const size_t row = (size_t)sent[b] * 300;
    for (int e = tid; e < 300; e += 64)
        X0[(size_t)b * 300 + e] = emb[row + e];
}

// ---------------- fp32 GEMM: C[M,N] = A[M,K] @ W[N,K]^T + bias[N] ----------------
__global__ __launch_bounds__(256)
void sgemm_bias(const float* __restrict__ A, const float* __restrict__ W,
                const float* __restrict__ bias, float* __restrict__ C,
                int M, int N, int K)
{
    __shared__ float As[8][128];
    __shared__ float Ws[8][128];
    const int tid = threadIdx.x;
    const int m0 = blockIdx.y * 128, n0 = blockIdx.x * 128;
    const int tx = tid & 15, ty = tid >> 4;
    const int lr = tid >> 1, lk = (tid & 1) * 4;
    float acc[8][8] = {};
    for (int k0 = 0; k0 < K; k0 += 8) {
#pragma unroll
        for (int u = 0; u < 4; ++u) {
            const int k = k0 + lk + u;
            As[lk + u][lr] = (k < K) ? A[(size_t)(m0 + lr) * K + k] : 0.f;
            Ws[lk + u][lr] = (k < K) ? W[(size_t)(n0 + lr) * K + k] : 0.f;
        }
        __syncthreads();
#pragma unroll
        for (int kk = 0; kk < 8; ++kk) {
            float a[8], b[8];
#pragma unroll
            for (int i = 0; i < 8; ++i) a[i] = As[kk][ty * 8 + i];
#pragma unroll
            for (int i = 0; i < 8; ++i) b[i] = Ws[kk][tx * 8 + i];
#pragma unroll
            for (int i = 0; i < 8; ++i)
#pragma unroll
                for (int j = 0; j < 8; ++j) acc[i][j] += a[i] * b[j];
        }
        __syncthreads();
    }
#pragma unroll
    for (int i = 0; i < 8; ++i) {
        const int m = m0 + ty * 8 + i;
#pragma unroll
        for (int j = 0; j < 8; ++j) {
            const int n = n0 + tx * 8 + j;
            C[(size_t)m * N + n] = acc[i][j] + bias[n];
        }
    }
}

// ---------------- LSTM recurrence, v10b ----------------
// Protocol = v6 (proven): agent-scope h+offset stores, mall-coherent
// (sc0 sc1) polls, double-buffered windows; skew<=1 induction unchanged
// (a WG stores h_t only after its barrier, which requires ALL its threads
// to have acquired all 32 lines of h_{t-1}; so buffer reuse at t cannot
// race any consumer of h_{t-2}).
// v10 deltas (all v6-safe constructs):
//  1) per-seg direct polling: thread (seg,rsub)'s dot needs only
//     h[seg*16..+16) = the 64B line produced by WG 'seg'. Poll it straight
//     into the dot's float4 regs. Removes the 128-thread relay, the LDS
//     h_sm hop, and one barrier; each wave proceeds when ITS line lands.
//     Traffic: each seg-line polled by exactly one 32-lane half-wave ->
//     2KB/WG/iter, same bytes as v6's relay poll (no congestion increase).
//  2) adaptive sleep-paced sampling: sleep (s_sleep, feedback: +1 on any
//     miss, -1 every 16 steps) before the first poll so it ARRIVES at the
//     mall just after the store does. v6 wasted ~2 of ~3.25 round
//     trips/step on mis-phased sampling (FETCH_SIZE arithmetic: 52MB poll
//     re-fetch). Also LOWERS mall request rate (v8 showed congestion).
//  3) zz double-buffer -> one __syncthreads per step. Reuse of zz[t&1] at
//     t+2 is fenced by the t+1 barrier; h_t vs h_{t+4} buffer/window
//     aliasing needs skew>=4, chain bounds skew<=1. Cross-launch leftovers
//     are cleared by the harness reset() memsets (zeros match no window).
__global__ __launch_bounds__(RTH, 1)
void lstm_rec(const float* __restrict__ pre_f, const float* __restrict__ pre_b,
              const float* __restrict__ whh_f, const float* __restrict__ whh_b,
              float* __restrict__ out,           // (4096 x 1024): fwd [0,512), bwd [512,1024)
              float* __restrict__ hbuf)          // this layer: 2 dirs x 2 bufs x 512
{
    const int g = blockIdx.x;
    const int dir = g & 1, slot = g >> 1;
    const float* pre = dir ? pre_b : pre_f;
    const float* whh = dir ? whh_b : whh_f;
    float* hb0 = hbuf + dir * 2 * HID;     // + (t&1)*HID selects the buffer

    const int tid = threadIdx.x;
    const int seg = tid >> 5;        // 0..31 (16-col segment = producer slot polled)
    const int rsub = tid & 31;       // 0..31

    // local row r = k*16 + j (k=gate, j=unit); global z-row = gate*512 + slot*16 + j
    const int k0g = rsub >> 4, j0 = rsub & 15;
    const int grow0 = k0g * HID + slot * UPS + j0;
    const int grow1 = (k0g + 2) * HID + slot * UPS + j0;

    float4 w0[4], w1[4];
    {
        const float4* p0 = (const float4*)(whh + (size_t)grow0 * HID + seg * 16);
        const float4* p1 = (const float4*)(whh + (size_t)grow1 * HID + seg * 16);
#pragma unroll
        for (int c = 0; c < 4; ++c) { w0[c] = p0[c]; w1[c] = p1[c]; }
    }

    // reducer-lane (tid<64) row mapping
    const int rr = tid & 63;
    const int growr = (rr >> 4) * HID + slot * UPS + (rr & 15);

    __shared__ float zz[2][64][33];
    float c_state = 0.f;
    int slp = 3;                      // sleep units (x~128cy) before first poll

    float pre_v = 0.f;
    if (tid < 64) pre_v = pre[(size_t)(dir ? (SEQ - 1) : 0) * 2048 + growr];

    for (int t = 0; t < SEQ; ++t) {
        const int tt = dir ? (SEQ - 1 - t) : t;
        const bool not_last = (t + 1 < SEQ);

        // loop-carried VGPR pin: volatile asm cannot be re-executed, so the
        // compiler must keep all 32 weight floats live across iterations.
        asm volatile("" : "+v"(w0[0].x), "+v"(w0[0].y), "+v"(w0[0].z), "+v"(w0[0].w),
                           "+v"(w0[1].x), "+v"(w0[1].y), "+v"(w0[1].z), "+v"(w0[1].w),
                           "+v"(w0[2].x), "+v"(w0[2].y), "+v"(w0[2].z), "+v"(w0[2].w),
                           "+v"(w0[3].x), "+v"(w0[3].y), "+v"(w0[3].z), "+v"(w0[3].w));
        asm volatile("" : "+v"(w1[0].x), "+v"(w1[0].y), "+v"(w1[0].z), "+v"(w1[0].w),
                           "+v"(w1[1].x), "+v"(w1[1].y), "+v"(w1[1].z), "+v"(w1[1].w),
                           "+v"(w1[2].x), "+v"(w1[2].y), "+v"(w1[2].z), "+v"(w1[2].w),
                           "+v"(w1[3].x), "+v"(w1[3].y), "+v"(w1[3].z), "+v"(w1[3].w));

        // -------- acquire h_{t-1}[seg*16..+16) directly into registers --------
        float4 h0, h1, h2, h3;
        if (t > 0) {
            const int tp = t - 1;
            const float lo = 2.f + 6.f * (float)((tp >> 1) & 1);
            const float hi = lo + 2.f;
            const float mid = lo + 1.f;
            const float* src = hb0 + (tp & 1) * HID + seg * 16;
            for (int sl = 0; sl < slp; ++sl) __builtin_amdgcn_s_sleep(2);
            int misses = 0;
            for (;;) {
                load_line_cc(src, h0, h1, h2, h3);
                if (ok4(h0, lo, hi) && ok4(h1, lo, hi) &&
                    ok4(h2, lo, hi) && ok4(h3, lo, hi)) break;
                ++misses;
            }
            h0.x -= mid; h0.y -= mid; h0.z -= mid; h0.w -= mid;
            h1.x -= mid; h1.y -= mid; h1.z -= mid; h1.w -= mid;
            h2.x -= mid; h2.y -= mid; h2.z -= mid; h2.w -= mid;
            h3.x -= mid; h3.y -= mid; h3.z -= mid; h3.w -= mid;
            // feedback: wave-uniform sleep adaptation (ballot -> same value
            // in every lane; misses cost a full mall round trip, so bias up)
            const unsigned long long anymiss = __ballot(misses > 0);
            if (anymiss != 0ull) { if (slp < 12) ++slp; }
            else if ((t & 15) == 1 && slp > 0) --slp;
        } else {
            h0 = make_float4(0.f, 0.f, 0.f, 0.f);
            h1 = h0; h2 = h0; h3 = h0;
        }

        // dot: 2 local rows x 16 cols against the polled registers
        float a0, a1;
        {
            a0  = w0[0].x*h0.x + w0[0].y*h0.y + w0[0].z*h0.z + w0[0].w*h0.w;
            a0 += w0[1].x*h1.x + w0[1].y*h1.y + w0[1].z*h1.z + w0[1].w*h1.w;
            a0 += w0[2].x*h2.x + w0[2].y*h2.y + w0[2].z*h2.z + w0[2].w*h2.w;
            a0 += w0[3].x*h3.x + w0[3].y*h3.y + w0[3].z*h3.z + w0[3].w*h3.w;
            a1  = w1[0].x*h0.x + w1[0].y*h0.y + w1[0].z*h0.z + w1[0].w*h0.w;
            a1 += w1[1].x*h1.x + w1[1].y*h1.y + w1[1].z*h1.z + w1[1].w*h1.w;
            a1 += w1[2].x*h2.x + w1[2].y*h2.y + w1[2].z*h2.z + w1[2].w*h2.w;
            a1 += w1[3].x*h3.x + w1[3].y*h3.y + w1[3].z*h3.z + w1[3].w*h3.w;
        }
        const int zb = t & 1;
        zz[zb][rsub][seg] = a0;
        zz[zb][rsub + 32][seg] = a1;
        __syncthreads();

        // prefetch next step's pre (latency hidden under reduce + next poll)
        float pre_next = 0.f;
        if (tid < 64 && not_last) {
            const int tn = dir ? (SEQ - 2 - t) : (t + 1);
            pre_next = pre[(size_t)tn * 2048 + growr];
        }

        if (tid < 64) {
            float s = pre_v;
#pragma unroll
            for (int c = 0; c < 32; ++c) s += zz[zb][tid][c];
            // gather the 4 gate pre-activations for unit lj within wave 0
            const int lj = tid & 15;
            const float zi = __shfl(s, lj, 64);
            const float zf = __shfl(s, lj + 16, 64);
            const float zg = __shfl(s, lj + 32, 64);
            const float zo = __shfl(s, lj + 48, 64);
            if (tid < UPS) {
                const float ig = sigf(zi), fg = sigf(zf), og = sigf(zo);
                c_state = fg * c_state + ig * tanhfast(zg);
                const float h = og * tanhfast(c_state);
                out[(size_t)tt * 1024 + dir * HID + slot * UPS + lj] = h;
                if (not_last) {
                    const float off = 3.f + 6.f * (float)((t >> 1) & 1);
                    __hip_atomic_store(hb0 + (t & 1) * HID + slot * UPS + lj, h + off,
                                       __ATOMIC_RELAXED, __HIP_MEMORY_SCOPE_AGENT);
                }
            }
        }
        // no second barrier: zz[t&1] is not rewritten until t+2, and the
        // t+1 barrier fences it; h-poll windows handle the global exchange.
        pre_v = pre_next;
    }
}

// ---------------- emissions: EM[4096,24] = X2[4096,1024] @ Wo[24,1024]^T + bo ----------------
__global__ __launch_bounds__(256)
void emissions_kernel(const float* __restrict__ X, const float* __restrict__ Wo,
                      const float* __restrict__ bo, float* __restrict__ EM)
{
    __shared__ float xs[1024];
    __shared__ float red[NT][9];
    const int t = blockIdx.x, tid = threadIdx.x;
    for (int i = tid; i < 1024; i += 256) xs[i] = X[(size_t)t * 1024 + i];
    __syncthreads();
    const int col = tid >> 3, s = tid & 7;
    if (col < NT) {
        float acc = 0.f;
        const float* wr = Wo + (size_t)col * 1024 + s * 128;
        const float* xp = xs + s * 128;
#pragma unroll 8
        for (int i = 0; i < 128; ++i) acc += wr[i] * xp[i];
        red[col][s] = acc;
    }
    __syncthreads();
    if (tid < NT) {
        float rsum = 0.f;
#pragma unroll
        for (int s2 = 0; s2 < 8; ++s2) rsum += red[tid][s2];
        EM[t * NT + tid] = rsum + bo[tid];
    }
}

// ---------------- numerator ----------------
__global__ __launch_bounds__(256)
void num_kernel(const float* __restrict__ EM, const int* __restrict__ tags,
                const float* __restrict__ stt, const float* __restrict__ ent,
                const float* __restrict__ tr, float* __restrict__ numout)
{
    __shared__ float red[256];
    const int tid = threadIdx.x;
    float acc = 0.f;
    for (int t = tid; t < SEQ; t += 256) {
        const int tg = tags[t];
        acc += EM[t * NT + tg];
        if (t < SEQ - 1) acc += tr[tg * NT + tags[t + 1]];
    }
    red[tid] = acc; __syncthreads();
    for (int s = 128; s > 0; s >>= 1) { if (tid < s) red[tid] += red[tid + s]; __syncthreads(); }
    if (tid == 0) numout[0] = red[0] + stt[tags[0]] + ent[tags[SEQ - 1]];
}

// ---------------- CRF stage 1: chunk products of M_t (t=1..4095), 16 per chunk ----------------
__global__ __launch_bounds__(576)
void crf_stage1(const float* __restrict__ EM, const float* __restrict__ trans,
                float* __restrict__ CH)
{
    __shared__ float tr[NT][NT];
    __shared__ float cur[2][NT][NT + 1];
    const int tid = threadIdx.x;
    const int i = tid / NT, j = tid % NT;
    const int c = blockIdx.x;
    const int t0 = 1 + c * 16;
    const int cm = min(16, SEQ - t0);
    const float trv = trans[i * NT + j];
    tr[i][j] = trv;
    cur[0][i][j] = trv + EM[t0 * NT + j];
    __syncthreads();
    int pp = 0;
    for (int s = 1; s < cm; ++s) {
        const float e = EM[(t0 + s) * NT + j];
        float m = -1e30f;
#pragma unroll
        for (int k = 0; k < NT; ++k) m = fmaxf(m, cur[pp][i][k] + tr[k][j]);
        float sum = 0.f;
#pragma unroll
        for (int k = 0; k < NT; ++k) sum += __expf(cur[pp][i][k] + tr[k][j] - m);
        cur[1 - pp][i][j] = m + __logf(sum) + e;
        pp = 1 - pp;
        __syncthreads();
    }
    CH[(size_t)c * 576 + i * NT + j] = cur[pp][i][j];
}

// ---------------- CRF combine ----------------
__global__ __launch_bounds__(576)
void crf_combine(const float* __restrict__ IN, float* __restrict__ OUT, int per)
{
    __shared__ float cur[2][NT][NT + 1];
    const int tid = threadIdx.x;
    const int i = tid / NT, j = tid % NT;
    const int c = blockIdx.x;
    const float* base = IN + (size_t)c * per * 576;
    cur[0][i][j] = base[i * NT + j];
    __syncthreads();
    int pp = 0;
    for (int s = 1; s < per; ++s) {
        const float* B = base + (size_t)s * 576;
        float m = -1e30f;
#pragma unroll
        for (int k = 0; k < NT; ++k) m = fmaxf(m, cur[pp][i][k] + B[k * NT + j]);
        float sum = 0.f;
#pragma unroll
        for (int k = 0; k < NT; ++k) sum += __expf(cur[pp][i][k] + B[k * NT + j] - m);
        cur[1 - pp][i][j] = m + __logf(sum);
        pp = 1 - pp;
        __syncthreads();
    }
    OUT[(size_t)c * 576 + i * NT + j] = cur[pp][i][j];
}

// ---------------- CRF final ----------------
__global__ __launch_bounds__(576)
void crf_final(const float* __restrict__ P2, const float* __restrict__ EM,
               const float* __restrict__ stt, const float* __restrict__ ent,
               const float* __restrict__ numptr, float* __restrict__ outp)
{
    __shared__ float cur[2][NT][NT + 1];
    __shared__ float red[1024];
    const int tid = threadIdx.x;
    const int i = tid / NT, j = tid % NT;
    cur[0][i][j] = P2[i * NT + j];
    __syncthreads();
    int pp = 0;
    for (int s = 1; s < 16; ++s) {
        const float* B = P2 + (size_t)s * 576;
        float m = -1e30f;
#pragma unroll
        for (int k = 0; k < NT; ++k) m = fmaxf(m, cur[pp][i][k] + B[k * NT + j]);
        float sum = 0.f;
#pragma unroll
        for (int k = 0; k < NT; ++k) sum += __expf(cur[pp][i][k] + B[k * NT + j] - m);
        cur[1 - pp][i][j] = m + __logf(sum);
        pp = 1 - pp;
        __syncthreads();
    }
    const float v = stt[i] + EM[i] + cur[pp][i][j] + ent[j];
    red[tid] = v;
    for (int t2 = tid + 576; t2 < 1024; t2 += 576) red[t2] = -1e30f;
    __syncthreads();
    for (int s2 = 512; s2 > 0; s2 >>= 1) {
        if (tid < s2) red[tid] = fmaxf(red[tid], red[tid + s2]);
        __syncthreads();
    }
    const float m = red[0];
    __syncthreads();
    red[tid] = __expf(v - m);
    for (int t2 = tid + 576; t2 < 1024; t2 += 576) red[t2] = 0.f;
    __syncthreads();
    for (int s2 = 512; s2 > 0; s2 >>= 1) {
        if (tid < s2) red[tid] += red[tid + s2];
        __syncthreads();
    }
    if (tid == 0) outp[0] = m + __logf(red[0]) - numptr[0];
}

// ---------------- launcher ----------------
extern "C" void kernel_launch(void* const* d_in, const int* in_sizes, int n_in,
                              void* d_out, int out_size, void* d_ws, size_t ws_size,
                              hipStream_t stream)
{
    const float* emb    = (const float*)d_in[0];
    const float* wih0f  = (const float*)d_in[1];
    const float* whh0f  = (const float*)d_in[2];
    const float* b0f    = (const float*)d_in[3];
    const float* wih0b  = (const float*)d_in[4];
    const float* whh0b  = (const float*)d_in[5];
    const float* b0b    = (const float*)d_in[6];
    const float* wih1f  = (const float*)d_in[7];
    const float* whh1f  = (const float*)d_in[8];
    const float* b1f    = (const float*)d_in[9];
    const float* wih1b  = (const float*)d_in[10];
    const float* whh1b  = (const float*)d_in[11];
    const float* b1b    = (const float*)d_in[12];
    const float* wout   = (const float*)d_in[13];
    const float* bout   = (const float*)d_in[14];
    const float* sttr   = (const float*)d_in[15];
    const float* entr   = (const float*)d_in[16];
    const float* trans  = (const float*)d_in[17];
    const int*   sent   = (const int*)d_in[18];
    const int*   tags   = (const int*)d_in[19];

    float* ws = (float*)d_ws;
    float* X0   = ws;                          // 4096*300
    float* PRE  = X0 + 1228800;                // 2 * 4096*2048
    float* X1   = PRE + 16777216;              // 4096*1024
    float* X2   = X1 + 4194304;                // 4096*1024
    float* EMb  = X2 + 4194304;                // 4096*24
    float* CH   = EMb + 98304;                 // 256*576
    float* P2   = CH + 147456;                 // 16*576
    float* NUMv = P2 + 9216;                   // 1 (padded 64)
    float* HBUF = NUMv + 64;                   // 2 layers x (2 dirs x 2 bufs x 512)

    const int PREST = 8388608; // per-direction stride in PRE

    init_gather<<<4096, 64, 0, stream>>>(emb, sent, X0);

    dim3 gg(16, 32);
    sgemm_bias<<<gg, 256, 0, stream>>>(X0, wih0f, b0f, PRE,         4096, 2048, 300);
    sgemm_bias<<<gg, 256, 0, stream>>>(X0, wih0b, b0b, PRE + PREST, 4096, 2048, 300);
    lstm_rec<<<2 * RK, RTH, 0, stream>>>(PRE, PRE + PREST, whh0f, whh0b, X1, HBUF);

    sgemm_bias<<<gg, 256, 0, stream>>>(X1, wih1f, b1f, PRE,         4096, 2048, 1024);
    sgemm_bias<<<gg, 256, 0, stream>>>(X1, wih1b, b1b, PRE + PREST, 4096, 2048, 1024);
    lstm_rec<<<2 * RK, RTH, 0, stream>>>(PRE, PRE + PREST, whh1f, whh1b, X2, HBUF + 2048);

    emissions_kernel<<<4096, 256, 0, stream>>>(X2, wout, bout, EMb);
    num_kernel<<<1, 256, 0, stream>>>(EMb, tags, sttr, entr, trans, NUMv);
    crf_stage1<<<256, 576, 0, stream>>>(EMb, trans, CH);
    crf_combine<<<16, 576, 0, stream>>>(CH, P2, 16);
    crf_final<<<1, 576, 0, stream>>>(P2, EMb, sttr, entr, NUMv, (float*)d_out);
}

// Round 6
// 16231.683 us; speedup vs baseline: 1.2861x; 1.2861x over previous
//
#include <hip/hip_runtime.h>

#define RK 32          // workgroups per LSTM direction
#define RTH 1024       // threads per recurrence WG
#define UPS 16         // hidden units per slot (512/RK)
#define SEQ 4096
#define HID 512
#define NT 24

__device__ __forceinline__ float sigf(float x) { return 1.f / (1.f + __expf(-x)); }
__device__ __forceinline__ float tanhfast(float x) {
    const float e = __expf(2.f * x);
    return 1.f - 2.f / (e + 1.f);
}

__device__ __forceinline__ bool ok4(const float4& v, float lo, float hi) {
    return v.x >= lo && v.x <= hi && v.y >= lo && v.y <= hi &&
           v.z >= lo && v.z <= hi && v.w >= lo && v.w <= hi;
}

// 16B load that bypasses L1/L2 -> coherent (L3/mall-resident for hot hbuf).
__device__ __forceinline__ float4 load_f4_cc(const float* p) {
    float4 v;
    asm volatile("global_load_dwordx4 %0, %1, off sc0 sc1\n\ts_waitcnt vmcnt(0)"
                 : "=v"(v) : "v"(p) : "memory");
    return v;
}

// ---------------- init: embedding gather ----------------
__global__ __launch_bounds__(64)
void init_gather(const float* __restrict__ emb, const int* __restrict__ sent,
                 float* __restrict__ X0)
{
    const int b = blockIdx.x, tid = threadIdx.x;
    const size_t row = (size_t)sent[b] * 300;
    for (int e = tid; e < 300; e += 64)
        X0[(size_t)b * 300 + e] = emb[row + e];
}

// ---------------- fp32 GEMM: C[M,N] = A[M,K] @ W[N,K]^T + bias[N] ----------------
__global__ __launch_bounds__(256)
void sgemm_bias(const float* __restrict__ A, const float* __restrict__ W,
                const float* __restrict__ bias, float* __restrict__ C,
                int M, int N, int K)
{
    __shared__ float As[8][128];
    __shared__ float Ws[8][128];
    const int tid = threadIdx.x;
    const int m0 = blockIdx.y * 128, n0 = blockIdx.x * 128;
    const int tx = tid & 15, ty = tid >> 4;
    const int lr = tid >> 1, lk = (tid & 1) * 4;
    float acc[8][8] = {};
    for (int k0 = 0; k0 < K; k0 += 8) {
#pragma unroll
        for (int u = 0; u < 4; ++u) {
            const int k = k0 + lk + u;
            As[lk + u][lr] = (k < K) ? A[(size_t)(m0 + lr) * K + k] : 0.f;
            Ws[lk + u][lr] = (k < K) ? W[(size_t)(n0 + lr) * K + k] : 0.f;
        }
        __syncthreads();
#pragma unroll
        for (int kk = 0; kk < 8; ++kk) {
            float a[8], b[8];
#pragma unroll
            for (int i = 0; i < 8; ++i) a[i] = As[kk][ty * 8 + i];
#pragma unroll
            for (int i = 0; i < 8; ++i) b[i] = Ws[kk][tx * 8 + i];
#pragma unroll
            for (int i = 0; i < 8; ++i)
#pragma unroll
                for (int j = 0; j < 8; ++j) acc[i][j] += a[i] * b[j];
        }
        __syncthreads();
    }
#pragma unroll
    for (int i = 0; i < 8; ++i) {
        const int m = m0 + ty * 8 + i;
#pragma unroll
        for (int j = 0; j < 8; ++j) {
            const int n = n0 + tx * 8 + j;
            C[(size_t)m * N + n] = acc[i][j] + bias[n];
        }
    }
}

// ---------------- LSTM recurrence, v12 ----------------
// Protocol byte-identical to v6 (proven 7356us/layer): agent-scope h+offset
// stores, coherent sc0sc1 16B polls by tid<128, h_sm relay, 2 barriers,
// double-buffered self-validating windows (skew<=1 proof unchanged).
// v12 = vmcnt HYGIENE only (post-mortem of v8/v10b: every poll check is
// s_waitcnt vmcnt(0), which waits on ALL outstanding VMEM in that wave;
// wave0 carried a ~900cy HBM pre-prefetch + out/h stores, so wave0's
// detection lagged wave1's and BARRIER2 takes the max):
//  1) pre prefetch moved to wave 8 (tid 512..575) -> LDS pre_sm[2][64],
//     consumed by reducers from LDS. Fencing: written between B1(t)/B2(t),
//     read after B1(t+1).
//  2) out store moved to wave 9 (tid 576..591) via LDS h_new[2][16] relay,
//     deferred one step; final row stored after the loop. Only the
//     latency-critical hbuf store remains on reducer lanes.
//  => polling lanes wait only on their own poll load (true L3 RT/sample).
//  3) zz reduce reassociated into 4 chains (shorter dep chain).
__global__ __launch_bounds__(RTH, 1)
void lstm_rec(const float* __restrict__ pre_f, const float* __restrict__ pre_b,
              const float* __restrict__ whh_f, const float* __restrict__ whh_b,
              float* __restrict__ out,           // (4096 x 1024): fwd [0,512), bwd [512,1024)
              float* __restrict__ hbuf)          // this layer: 2 dirs x 2 bufs x 512
{
    const int g = blockIdx.x;
    const int dir = g & 1, slot = g >> 1;
    const float* pre = dir ? pre_b : pre_f;
    const float* whh = dir ? whh_b : whh_f;
    float* hb0 = hbuf + dir * 2 * HID;     // + (t&1)*HID selects the buffer

    const int tid = threadIdx.x;
    const int seg = tid >> 5;        // 0..31 (16-col segment)
    const int rsub = tid & 31;       // 0..31

    // local row r = k*16 + j (k=gate, j=unit); global z-row = gate*512 + slot*16 + j
    const int k0g = rsub >> 4, j0 = rsub & 15;
    const int grow0 = k0g * HID + slot * UPS + j0;
    const int grow1 = (k0g + 2) * HID + slot * UPS + j0;

    float4 w0[4], w1[4];
    {
        const float4* p0 = (const float4*)(whh + (size_t)grow0 * HID + seg * 16);
        const float4* p1 = (const float4*)(whh + (size_t)grow1 * HID + seg * 16);
#pragma unroll
        for (int c = 0; c < 4; ++c) { w0[c] = p0[c]; w1[c] = p1[c]; }
    }

    // 64-row mapping shared by reducers (tid<64) and the prefetch wave (tid&63)
    const int rr = tid & 63;
    const int growr = (rr >> 4) * HID + slot * UPS + (rr & 15);

    __shared__ float h_sm[HID];
    __shared__ float zz[64][33];
    __shared__ float pre_sm[2][64];
    __shared__ float h_new[2][16];
    float c_state = 0.f;

    if (tid < HID) h_sm[tid] = 0.f;
    if (tid < 64) {
        const int t0row = dir ? (SEQ - 1) : 0;
        pre_sm[0][tid] = pre[(size_t)t0row * 2048 + growr];
    }
    __syncthreads();

    for (int t = 0; t < SEQ; ++t) {
        const bool not_last = (t + 1 < SEQ);

        // loop-carried VGPR pin: volatile asm cannot be re-executed, so the
        // compiler must keep all 32 weight floats live across iterations.
        asm volatile("" : "+v"(w0[0].x), "+v"(w0[0].y), "+v"(w0[0].z), "+v"(w0[0].w),
                           "+v"(w0[1].x), "+v"(w0[1].y), "+v"(w0[1].z), "+v"(w0[1].w),
                           "+v"(w0[2].x), "+v"(w0[2].y), "+v"(w0[2].z), "+v"(w0[2].w),
                           "+v"(w0[3].x), "+v"(w0[3].y), "+v"(w0[3].z), "+v"(w0[3].w));
        asm volatile("" : "+v"(w1[0].x), "+v"(w1[0].y), "+v"(w1[0].z), "+v"(w1[0].w),
                           "+v"(w1[1].x), "+v"(w1[1].y), "+v"(w1[1].z), "+v"(w1[1].w),
                           "+v"(w1[2].x), "+v"(w1[2].y), "+v"(w1[2].z), "+v"(w1[2].w),
                           "+v"(w1[3].x), "+v"(w1[3].y), "+v"(w1[3].z), "+v"(w1[3].w));

        // dot: 2 local rows x 16 cols against h_sm[seg*16 ..]
        const float4* hp = (const float4*)(h_sm + seg * 16);
        const float4 h0 = hp[0], h1 = hp[1], h2 = hp[2], h3 = hp[3];
        float a0, a1;
        {
            a0  = w0[0].x*h0.x + w0[0].y*h0.y + w0[0].z*h0.z + w0[0].w*h0.w;
            a0 += w0[1].x*h1.x + w0[1].y*h1.y + w0[1].z*h1.z + w0[1].w*h1.w;
            a0 += w0[2].x*h2.x + w0[2].y*h2.y + w0[2].z*h2.z + w0[2].w*h2.w;
            a0 += w0[3].x*h3.x + w0[3].y*h3.y + w0[3].z*h3.z + w0[3].w*h3.w;
            a1  = w1[0].x*h0.x + w1[0].y*h0.y + w1[0].z*h0.z + w1[0].w*h0.w;
            a1 += w1[1].x*h1.x + w1[1].y*h1.y + w1[1].z*h1.z + w1[1].w*h1.w;
            a1 += w1[2].x*h2.x + w1[2].y*h2.y + w1[2].z*h2.z + w1[2].w*h2.w;
            a1 += w1[3].x*h3.x + w1[3].y*h3.y + w1[3].z*h3.z + w1[3].w*h3.w;
        }
        zz[rsub][seg] = a0;
        zz[rsub + 32][seg] = a1;
        __syncthreads();                                   // BARRIER1

        // wave 8: prefetch next step's pre row into LDS (keeps the ~900cy
        // HBM load out of the polling/reducing waves' vmcnt queues)
        if (tid >= 512 && tid < 576 && not_last) {
            const int tn = dir ? (SEQ - 2 - t) : (t + 1);
            pre_sm[(t + 1) & 1][rr] = pre[(size_t)tn * 2048 + growr];
        }

        // wave 9: deferred out-store of the PREVIOUS step's h (not on the
        // critical path; keeps the store out of polling waves)
        if (tid >= 576 && tid < 592 && t > 0) {
            const int lj = tid - 576;
            const int ttp = dir ? (SEQ - t) : (t - 1);     // tt of step t-1
            out[(size_t)ttp * 1024 + dir * HID + slot * UPS + lj] =
                h_new[(t + 1) & 1][lj];
        }

        if (tid < 64) {
            float s0 = 0.f, s1 = 0.f, s2 = 0.f, s3 = 0.f;
#pragma unroll
            for (int c = 0; c < 8; ++c) {
                s0 += zz[tid][c];
                s1 += zz[tid][c + 8];
                s2 += zz[tid][c + 16];
                s3 += zz[tid][c + 24];
            }
            const float s = pre_sm[t & 1][tid] + ((s0 + s1) + (s2 + s3));
            // gather the 4 gate pre-activations for unit lj within wave 0
            const int lj = tid & 15;
            const float zi = __shfl(s, lj, 64);
            const float zf = __shfl(s, lj + 16, 64);
            const float zg = __shfl(s, lj + 32, 64);
            const float zo = __shfl(s, lj + 48, 64);
            if (tid < UPS) {
                const float ig = sigf(zi), fg = sigf(zf), og = sigf(zo);
                c_state = fg * c_state + ig * tanhfast(zg);
                const float h = og * tanhfast(c_state);
                h_new[t & 1][lj] = h;                      // relay for wave 9
                if (not_last) {
                    const float off = 3.f + 6.f * (float)((t >> 1) & 1);
                    __hip_atomic_store(hb0 + (t & 1) * HID + slot * UPS + lj, h + off,
                                       __ATOMIC_RELAXED, __HIP_MEMORY_SCOPE_AGENT);
                }
            }
        }

        if (not_last) {
            if (tid < 128) {
                const float lo = 2.f + 6.f * (float)((t >> 1) & 1);
                const float hi = lo + 2.f;
                const float mid = lo + 1.f;
                const float* src = hb0 + (t & 1) * HID + tid * 4;
                float4 v;
                for (;;) {
                    v = load_f4_cc(src);
                    if (ok4(v, lo, hi)) break;
                }
                float4* dst = (float4*)(h_sm + tid * 4);
                *dst = make_float4(v.x - mid, v.y - mid, v.z - mid, v.w - mid);
            }
            __syncthreads();                               // BARRIER2
        }
    }

    // final step's out row (wave 9's in-loop store covers t-1 only)
    __syncthreads();
    if (tid >= 576 && tid < 592) {
        const int lj = tid - 576;
        const int ttl = dir ? 0 : (SEQ - 1);
        out[(size_t)ttl * 1024 + dir * HID + slot * UPS + lj] =
            h_new[(SEQ - 1) & 1][lj];
    }
}

// ---------------- emissions: EM[4096,24] = X2[4096,1024] @ Wo[24,1024]^T + bo ----------------
__global__ __launch_bounds__(256)
void emissions_kernel(const float* __restrict__ X, const float* __restrict__ Wo,
                      const float* __restrict__ bo, float* __restrict__ EM)
{
    __shared__ float xs[1024];
    __shared__ float red[NT][9];
    const int t = blockIdx.x, tid = threadIdx.x;
    for (int i = tid; i < 1024; i += 256) xs[i] = X[(size_t)t * 1024 + i];
    __syncthreads();
    const int col = tid >> 3, s = tid & 7;
    if (col < NT) {
        float acc = 0.f;
        const float* wr = Wo + (size_t)col * 1024 + s * 128;
        const float* xp = xs + s * 128;
#pragma unroll 8
        for (int i = 0; i < 128; ++i) acc += wr[i] * xp[i];
        red[col][s] = acc;
    }
    __syncthreads();
    if (tid < NT) {
        float rsum = 0.f;
#pragma unroll
        for (int s2 = 0; s2 < 8; ++s2) rsum += red[tid][s2];
        EM[t * NT + tid] = rsum + bo[tid];
    }
}

// ---------------- numerator ----------------
__global__ __launch_bounds__(256)
void num_kernel(const float* __restrict__ EM, const int* __restrict__ tags,
                const float* __restrict__ stt, const float* __restrict__ ent,
                const float* __restrict__ tr, float* __restrict__ numout)
{
    __shared__ float red[256];
    const int tid = threadIdx.x;
    float acc = 0.f;
    for (int t = tid; t < SEQ; t += 256) {
        const int tg = tags[t];
        acc += EM[t * NT + tg];
        if (t < SEQ - 1) acc += tr[tg * NT + tags[t + 1]];
    }
    red[tid] = acc; __syncthreads();
    for (int s = 128; s > 0; s >>= 1) { if (tid < s) red[tid] += red[tid + s]; __syncthreads(); }
    if (tid == 0) numout[0] = red[0] + stt[tags[0]] + ent[tags[SEQ - 1]];
}

// ---------------- CRF stage 1: chunk products of M_t (t=1..4095), 16 per chunk ----------------
__global__ __launch_bounds__(576)
void crf_stage1(const float* __restrict__ EM, const float* __restrict__ trans,
                float* __restrict__ CH)
{
    __shared__ float tr[NT][NT];
    __shared__ float cur[2][NT][NT + 1];
    const int tid = threadIdx.x;
    const int i = tid / NT, j = tid % NT;
    const int c = blockIdx.x;
    const int t0 = 1 + c * 16;
    const int cm = min(16, SEQ - t0);
    const float trv = trans[i * NT + j];
    tr[i][j] = trv;
    cur[0][i][j] = trv + EM[t0 * NT + j];
    __syncthreads();
    int pp = 0;
    for (int s = 1; s < cm; ++s) {
        const float e = EM[(t0 + s) * NT + j];
        float m = -1e30f;
#pragma unroll
        for (int k = 0; k < NT; ++k) m = fmaxf(m, cur[pp][i][k] + tr[k][j]);
        float sum = 0.f;
#pragma unroll
        for (int k = 0; k < NT; ++k) sum += __expf(cur[pp][i][k] + tr[k][j] - m);
        cur[1 - pp][i][j] = m + __logf(sum) + e;
        pp = 1 - pp;
        __syncthreads();
    }
    CH[(size_t)c * 576 + i * NT + j] = cur[pp][i][j];
}

// ---------------- CRF combine ----------------
__global__ __launch_bounds__(576)
void crf_combine(const float* __restrict__ IN, float* __restrict__ OUT, int per)
{
    __shared__ float cur[2][NT][NT + 1];
    const int tid = threadIdx.x;
    const int i = tid / NT, j = tid % NT;
    const int c = blockIdx.x;
    const float* base = IN + (size_t)c * per * 576;
    cur[0][i][j] = base[i * NT + j];
    __syncthreads();
    int pp = 0;
    for (int s = 1; s < per; ++s) {
        const float* B = base + (size_t)s * 576;
        float m = -1e30f;
#pragma unroll
        for (int k = 0; k < NT; ++k) m = fmaxf(m, cur[pp][i][k] + B[k * NT + j]);
        float sum = 0.f;
#pragma unroll
        for (int k = 0; k < NT; ++k) sum += __expf(cur[pp][i][k] + B[k * NT + j] - m);
        cur[1 - pp][i][j] = m + __logf(sum);
        pp = 1 - pp;
        __syncthreads();
    }
    OUT[(size_t)c * 576 + i * NT + j] = cur[pp][i][j];
}

// ---------------- CRF final ----------------
__global__ __launch_bounds__(576)
void crf_final(const float* __restrict__ P2, const float* __restrict__ EM,
               const float* __restrict__ stt, const float* __restrict__ ent,
               const float* __restrict__ numptr, float* __restrict__ outp)
{
    __shared__ float cur[2][NT][NT + 1];
    __shared__ float red[1024];
    const int tid = threadIdx.x;
    const int i = tid / NT, j = tid % NT;
    cur[0][i][j] = P2[i * NT + j];
    __syncthreads();
    int pp = 0;
    for (int s = 1; s < 16; ++s) {
        const float* B = P2 + (size_t)s * 576;
        float m = -1e30f;
#pragma unroll
        for (int k = 0; k < NT; ++k) m = fmaxf(m, cur[pp][i][k] + B[k * NT + j]);
        float sum = 0.f;
#pragma unroll
        for (int k = 0; k < NT; ++k) sum += __expf(cur[pp][i][k] + B[k * NT + j] - m);
        cur[1 - pp][i][j] = m + __logf(sum);
        pp = 1 - pp;
        __syncthreads();
    }
    const float v = stt[i] + EM[i] + cur[pp][i][j] + ent[j];
    red[tid] = v;
    for (int t2 = tid + 576; t2 < 1024; t2 += 576) red[t2] = -1e30f;
    __syncthreads();
    for (int s2 = 512; s2 > 0; s2 >>= 1) {
        if (tid < s2) red[tid] = fmaxf(red[tid], red[tid + s2]);
        __syncthreads();
    }
    const float m = red[0];
    __syncthreads();
    red[tid] = __expf(v - m);
    for (int t2 = tid + 576; t2 < 1024; t2 += 576) red[t2] = 0.f;
    __syncthreads();
    for (int s2 = 512; s2 > 0; s2 >>= 1) {
        if (tid < s2) red[tid] += red[tid + s2];
        __syncthreads();
    }
    if (tid == 0) outp[0] = m + __logf(red[0]) - numptr[0];
}

// ---------------- launcher ----------------
extern "C" void kernel_launch(void* const* d_in, const int* in_sizes, int n_in,
                              void* d_out, int out_size, void* d_ws, size_t ws_size,
                              hipStream_t stream)
{
    const float* emb    = (const float*)d_in[0];
    const float* wih0f  = (const float*)d_in[1];
    const float* whh0f  = (const float*)d_in[2];
    const float* b0f    = (const float*)d_in[3];
    const float* wih0b  = (const float*)d_in[4];
    const float* whh0b  = (const float*)d_in[5];
    const float* b0b    = (const float*)d_in[6];
    const float* wih1f  = (const float*)d_in[7];
    const float* whh1f  = (const float*)d_in[8];
    const float* b1f    = (const float*)d_in[9];
    const float* wih1b  = (const float*)d_in[10];
    const float* whh1b  = (const float*)d_in[11];
    const float* b1b    = (const float*)d_in[12];
    const float* wout   = (const float*)d_in[13];
    const float* bout   = (const float*)d_in[14];
    const float* sttr   = (const float*)d_in[15];
    const float* entr   = (const float*)d_in[16];
    const float* trans  = (const float*)d_in[17];
    const int*   sent   = (const int*)d_in[18];
    const int*   tags   = (const int*)d_in[19];

    float* ws = (float*)d_ws;
    float* X0   = ws;                          // 4096*300
    float* PRE  = X0 + 1228800;                // 2 * 4096*2048
    float* X1   = PRE + 16777216;              // 4096*1024
    float* X2   = X1 + 4194304;                // 4096*1024
    float* EMb  = X2 + 4194304;                // 4096*24
    float* CH   = EMb + 98304;                 // 256*576
    float* P2   = CH + 147456;                 // 16*576
    float* NUMv = P2 + 9216;                   // 1 (padded 64)
    float* HBUF = NUMv + 64;                   // 2 layers x (2 dirs x 2 bufs x 512)

    const int PREST = 8388608; // per-direction stride in PRE

    init_gather<<<4096, 64, 0, stream>>>(emb, sent, X0);

    dim3 gg(16, 32);
    sgemm_bias<<<gg, 256, 0, stream>>>(X0, wih0f, b0f, PRE,         4096, 2048, 300);
    sgemm_bias<<<gg, 256, 0, stream>>>(X0, wih0b, b0b, PRE + PREST, 4096, 2048, 300);
    lstm_rec<<<2 * RK, RTH, 0, stream>>>(PRE, PRE + PREST, whh0f, whh0b, X1, HBUF);

    sgemm_bias<<<gg, 256, 0, stream>>>(X1, wih1f, b1f, PRE,         4096, 2048, 1024);
    sgemm_bias<<<gg, 256, 0, stream>>>(X1, wih1b, b1b, PRE + PREST, 4096, 2048, 1024);
    lstm_rec<<<2 * RK, RTH, 0, stream>>>(PRE, PRE + PREST, whh1f, whh1b, X2, HBUF + 2048);

    emissions_kernel<<<4096, 256, 0, stream>>>(X2, wout, bout, EMb);
    num_kernel<<<1, 256, 0, stream>>>(EMb, tags, sttr, entr, trans, NUMv);
    crf_stage1<<<256, 576, 0, stream>>>(EMb, trans, CH);
    crf_combine<<<16, 576, 0, stream>>>(CH, P2, 16);
    crf_final<<<1, 576, 0, stream>>>(P2, EMb, sttr, entr, NUMv, (float*)d_out);
}